// Round 8
// baseline (419.408 us; speedup 1.0000x reference)
//
#include <hip/hip_runtime.h>

// ---------------------------------------------------------------------------
// GAT encoder: x --GATConv(2 heads,128)--> ELU --> {GATConv mu, GATConv ls}
// N=50000, E=800000 (+self loops). fp32 in/out. Edges int32 w/ int64 detect.
// Round 8:
//  * GEMM v3: wave owns 32 rows (2 m-tiles) -> 32 MFMA/chunk/wave; A frags +
//    next B chunk register-prefetched during compute (no global stall at the
//    barrier). Block 128 thr (2 waves), grid n/64.
//  * k_agg v4: unroll 8; exp computed lane-parallel (one (edge,slot) per lane,
//    shfl broadcast) instead of duplicated across the 16/32-lane slot group;
//    fma_mix-friendly fp16 accumulate (no explicit cvts); u32 gather offsets.
//  * cvt+tw merged into k_prep.
//  k_agg FETCH 210MB = 8 XCDs x 25.6MB h = compulsory L3 traffic (random
//  graph) - structural floor; this round attacks its VALU share.
// ---------------------------------------------------------------------------

typedef unsigned short u16;
typedef unsigned int u32;
typedef _Float16 f16;
typedef f16 f16x8 __attribute__((ext_vector_type(8)));
typedef float f32x4v __attribute__((ext_vector_type(4)));

__device__ __forceinline__ u16 f2h(float f) {
    union { f16 h; u16 u; } t;
    t.h = (f16)f;
    return t.u;
}
__device__ __forceinline__ float4 loadh4(const u16* __restrict__ p, u32 i) {
    union { uint2 u; f16 h[4]; } t;
    t.u = *(const uint2*)(p + i);
    return make_float4((float)t.h[0], (float)t.h[1], (float)t.h[2], (float)t.h[3]);
}
__device__ __forceinline__ void store4(float* __restrict__ p, size_t i, float4 v) {
    *(float4*)(p + i) = v;
}
__device__ __forceinline__ void store4(u16* __restrict__ p, size_t i, float4 v) {
    union { uint2 u; f16 h[4]; } t;
    t.h[0] = (f16)v.x; t.h[1] = (f16)v.y; t.h[2] = (f16)v.z; t.h[3] = (f16)v.w;
    *(uint2*)(p + i) = t.u;
}

// ---------------- edge dtype detect + normalize (+degree count) --------------
__global__ __launch_bounds__(256) void k_detect(const u32* __restrict__ ebuf,
                                                int* __restrict__ flag) {
    __shared__ int nz;
    if (threadIdx.x == 0) nz = 0;
    __syncthreads();
    if (ebuf[2 * threadIdx.x + 1] != 0u) atomicAdd(&nz, 1);
    __syncthreads();
    if (threadIdx.x == 0) *flag = (nz == 0) ? 1 : 0;
}

__global__ __launch_bounds__(256) void k_extract(const u32* __restrict__ ebuf, int E,
                                                 const int* __restrict__ flag,
                                                 int* __restrict__ se,
                                                 int* __restrict__ de,
                                                 int* __restrict__ deg) {
    int e = blockIdx.x * 256 + threadIdx.x;
    if (e >= E) return;
    int s, d;
    if (*flag) {  // int64 layout
        s = (int)ebuf[2 * (size_t)e];
        d = (int)ebuf[2 * ((size_t)E + (size_t)e)];
    } else {  // int32 layout
        s = (int)ebuf[e];
        d = (int)ebuf[(size_t)E + (size_t)e];
    }
    se[e] = s;
    de[e] = d;
    atomicAdd(&deg[d], 1);
}

// ---------------- CSR build ----------------
__global__ __launch_bounds__(256) void k_scan_a(const int* __restrict__ deg, int n,
                                                int* __restrict__ bsum) {
    __shared__ int s[256];
    int i = blockIdx.x * 256 + threadIdx.x;
    s[threadIdx.x] = (i < n) ? deg[i] : 0;
    __syncthreads();
    for (int st = 128; st > 0; st >>= 1) {
        if (threadIdx.x < st) s[threadIdx.x] += s[threadIdx.x + st];
        __syncthreads();
    }
    if (threadIdx.x == 0) bsum[blockIdx.x] = s[0];
}

__global__ __launch_bounds__(256) void k_scan_b(int* __restrict__ bsum, int nb) {
    __shared__ int s[256];
    int t = threadIdx.x;
    int v = (t < nb) ? bsum[t] : 0;
    s[t] = v;
    __syncthreads();
    for (int off = 1; off < 256; off <<= 1) {
        int add = (t >= off) ? s[t - off] : 0;
        __syncthreads();
        s[t] += add;
        __syncthreads();
    }
    if (t < nb) bsum[t] = s[t] - v;  // exclusive
}

__global__ __launch_bounds__(256) void k_scan_c(const int* __restrict__ deg, int n,
                                                const int* __restrict__ bsum,
                                                int* __restrict__ rowptr,
                                                int* __restrict__ cursor, int E) {
    __shared__ int s[256];
    int t = threadIdx.x;
    int i = blockIdx.x * 256 + t;
    int v = (i < n) ? deg[i] : 0;
    s[t] = v;
    __syncthreads();
    for (int off = 1; off < 256; off <<= 1) {
        int add = (t >= off) ? s[t - off] : 0;
        __syncthreads();
        s[t] += add;
        __syncthreads();
    }
    if (i < n) {
        int ex = bsum[blockIdx.x] + s[t] - v;
        rowptr[i] = ex;
        cursor[i] = ex;
    }
    if (i == 0) rowptr[n] = E;
}

__global__ __launch_bounds__(256) void k_fill(const int* __restrict__ src,
                                              const int* __restrict__ dst, int E,
                                              int* __restrict__ cursor,
                                              int* __restrict__ csr_src) {
    int e = blockIdx.x * 256 + threadIdx.x;
    if (e < E) {
        int d = dst[e];
        int slot = atomicAdd(&cursor[d], 1);
        csr_src[slot] = src[e];
    }
}

// ---------------- merged prep: x->fp16, W1^T, [Wmu|Wls]^T -------------------
__global__ __launch_bounds__(256) void k_prep(const float* __restrict__ x,
                                              u16* __restrict__ xh, int B0, int nx4,
                                              const float* __restrict__ W1,
                                              u16* __restrict__ W1t,
                                              const float* __restrict__ Wmu,
                                              const float* __restrict__ Wls,
                                              u16* __restrict__ Wt2) {
    int b = blockIdx.x;
    int t = threadIdx.x;
    if (b < B0) {  // cvt x: float4 groups
        int g = b * 256 + t;
        if (g < nx4) {
            float4 v = *(const float4*)(x + (size_t)g * 4);
            store4(xh, (size_t)g * 4, v);
        }
    } else if (b < B0 + 128) {  // W1t[c][k]=W1[k][c], K=128
        int idx = (b - B0) * 256 + t;
        int c = idx >> 7, k = idx & 127;
        W1t[idx] = f2h(W1[(size_t)k * 256 + c]);
    } else {  // Wt2[c][k], K=256, split 128
        int idx = (b - B0 - 128) * 256 + t;
        int c = idx >> 8, k = idx & 255;
        float v = (c < 128) ? Wmu[(size_t)k * 128 + c]
                            : Wls[(size_t)k * 128 + (c - 128)];
        Wt2[idx] = f2h(v);
    }
}

// ---------------- MFMA GEMM v3 + fused alpha epilogue ------------------------
// h[M,256](f16) = A[M,K](f16) @ W[K,256]; Wt = W^T fp16 [256][K].
// Block 128 thr = 2 waves; wave owns 32 rows (2 m-tiles of 16); per 32-K chunk
// Bs (256x32, rows padded to 40) shared; next chunk's B (regs) + A frags
// prefetched during compute. mfma_f32_16x16x32_f16, HW-verified layouts.
// Epilogue: as/ad[row,slot] from fp32 accs. ALOGW=5 -> 2 slots; 4 -> 4 slots.
template <int K, int ALOGW>
__global__ __launch_bounds__(128, 2) void k_gemm_mfma(
    const u16* __restrict__ Ah, const u16* __restrict__ Wt, u16* __restrict__ out,
    float* __restrict__ as_out, float* __restrict__ ad_out,
    const float* __restrict__ alo, const float* __restrict__ ahi,
    const float* __restrict__ dlo, const float* __restrict__ dhi, int M) {
    __shared__ u16 Bs[256 * 40];  // 20KB
    const int tid = threadIdx.x;
    const int wave = tid >> 6;
    const int lane = tid & 63;
    const int li = lane & 15;
    const int quad = lane >> 4;
    const int r0 = blockIdx.x * 64 + wave * 32;

    int ar0 = r0 + li;
    if (ar0 >= M) ar0 = M - 1;
    int ar1 = r0 + 16 + li;
    if (ar1 >= M) ar1 = M - 1;
    const u16* arow0 = Ah + (size_t)ar0 * K + quad * 8;
    const u16* arow1 = Ah + (size_t)ar1 * K + quad * 8;

    f32x4v acc[2][16];
#pragma unroll
    for (int mt = 0; mt < 2; mt++)
#pragma unroll
        for (int ct = 0; ct < 16; ct++) acc[mt][ct] = (f32x4v)(0.f);

    // preload chunk 0: B (2 cols/thread) + A frags
    const int c0 = tid, c1 = tid + 128;
    uint4 br[2][4];
#pragma unroll
    for (int i = 0; i < 4; i++) {
        br[0][i] = ((const uint4*)(Wt + (size_t)c0 * K))[i];
        br[1][i] = ((const uint4*)(Wt + (size_t)c1 * K))[i];
    }
    f16x8 a0 = *(const f16x8*)(arow0);
    f16x8 a1 = *(const f16x8*)(arow1);

    for (int t = 0; t < K; t += 32) {
        __syncthreads();  // Bs readers of previous chunk done
        ((uint4*)(Bs + c0 * 40))[0] = br[0][0];
        ((uint4*)(Bs + c0 * 40 + 8))[0] = br[0][1];
        ((uint4*)(Bs + c0 * 40 + 16))[0] = br[0][2];
        ((uint4*)(Bs + c0 * 40 + 24))[0] = br[0][3];
        ((uint4*)(Bs + c1 * 40))[0] = br[1][0];
        ((uint4*)(Bs + c1 * 40 + 8))[0] = br[1][1];
        ((uint4*)(Bs + c1 * 40 + 16))[0] = br[1][2];
        ((uint4*)(Bs + c1 * 40 + 24))[0] = br[1][3];
        __syncthreads();
        f16x8 a0n, a1n;
        if (t + 32 < K) {  // prefetch next chunk during compute
#pragma unroll
            for (int i = 0; i < 4; i++) {
                br[0][i] = ((const uint4*)(Wt + (size_t)c0 * K + t + 32))[i];
                br[1][i] = ((const uint4*)(Wt + (size_t)c1 * K + t + 32))[i];
            }
            a0n = *(const f16x8*)(arow0 + t + 32);
            a1n = *(const f16x8*)(arow1 + t + 32);
        }
#pragma unroll
        for (int ct = 0; ct < 16; ct++) {
            f16x8 b = *(const f16x8*)(Bs + (ct * 16 + li) * 40 + quad * 8);
            acc[0][ct] = __builtin_amdgcn_mfma_f32_16x16x32_f16(a0, b, acc[0][ct], 0, 0, 0);
            acc[1][ct] = __builtin_amdgcn_mfma_f32_16x16x32_f16(a1, b, acc[1][ct], 0, 0, 0);
        }
        a0 = a0n;
        a1 = a1n;
    }

    // h store (fp16): D row = quad*4+reg, col = ct*16+li
#pragma unroll
    for (int mt = 0; mt < 2; mt++) {
#pragma unroll
        for (int reg = 0; reg < 4; reg++) {
            int grow = r0 + mt * 16 + quad * 4 + reg;
            if (grow < M) {
                u16* orow = out + (size_t)grow * 256 + li;
#pragma unroll
                for (int ct = 0; ct < 16; ct++) orow[ct * 16] = f2h(acc[mt][ct][reg]);
            }
        }
    }

    // fused alpha epilogue
    const int NS = 64 >> ALOGW;
    const int SH = ALOGW - 2;  // slot = ct >> SH
    float aw[16], dw[16];
#pragma unroll
    for (int ct = 0; ct < 16; ct++) {
        int col = ct * 16 + li;
        aw[ct] = (col < 128) ? alo[col] : ahi[col - 128];
        dw[ct] = (col < 128) ? dlo[col] : dhi[col - 128];
    }
#pragma unroll
    for (int mt = 0; mt < 2; mt++) {
#pragma unroll
        for (int reg = 0; reg < 4; reg++) {
            float s[4] = {0.f, 0.f, 0.f, 0.f};
            float d[4] = {0.f, 0.f, 0.f, 0.f};
#pragma unroll
            for (int ct = 0; ct < 16; ct++) {
                int sl = ct >> SH;
                s[sl] += acc[mt][ct][reg] * aw[ct];
                d[sl] += acc[mt][ct][reg] * dw[ct];
            }
#pragma unroll
            for (int sl = 0; sl < NS; sl++) {
#pragma unroll
                for (int m = 1; m <= 8; m <<= 1) {
                    s[sl] += __shfl_xor(s[sl], m, 64);
                    d[sl] += __shfl_xor(d[sl], m, 64);
                }
            }
            int grow = r0 + mt * 16 + quad * 4 + reg;
            if (li == 0 && grow < M) {
#pragma unroll
                for (int sl = 0; sl < NS; sl++) {
                    as_out[(size_t)grow * NS + sl] = s[sl];
                    ad_out[(size_t)grow * NS + sl] = d[sl];
                }
            }
        }
    }
}

// ---------------- aggregation v4 (softmax-weighted gather) -------------------
// One wave per dst node; lane owns 4 channels (fp16 h). Unroll 8: lanes
// 0..8*NS-1 each compute one (edge, slot) weight (exp issued once, not
// duplicated per slot-group), then shfl-broadcast. fp16 operands feed
// v_fma_mix-style accumulate. MODE 0: bias+ELU -> fp16 x1. MODE 1: fp32 mu/ls.
template <int LOGW, int MODE, typename OT>
__global__ __launch_bounds__(256) void k_agg(const u16* __restrict__ h,
                                             const int* __restrict__ rowptr,
                                             const int* __restrict__ csr_src,
                                             const float* __restrict__ as,
                                             const float* __restrict__ ad,
                                             const float* __restrict__ b_lo,
                                             const float* __restrict__ b_hi,
                                             OT* __restrict__ outp, int n) {
    const int NS = 64 >> LOGW;
    int wid = blockIdx.x * 4 + (threadIdx.x >> 6);
    int lane = threadIdx.x & 63;
    if (wid >= n) return;
    int slot = lane >> LOGW;       // own slot (channel phase)
    int wsl = (lane >> 3) & (NS - 1);  // weight-phase slot
    int i8 = lane & 7;             // weight-phase edge index
    int c = lane * 4;

    float adv_own = ad[(u32)wid * NS + slot];
    float adv_w = ad[(u32)wid * NS + wsl];

    // self-loop
    float e = as[(u32)wid * NS + slot] + adv_own;
    e = fmaxf(e, 0.2f * e);
    float w = __expf(e);
    float denom = w;
    float acc0, acc1, acc2, acc3;
    {
        union { uint2 u; f16 hh[4]; } t;
        t.u = *(const uint2*)(h + ((u32)wid << 8) + c);
        acc0 = w * (float)t.hh[0];
        acc1 = w * (float)t.hh[1];
        acc2 = w * (float)t.hh[2];
        acc3 = w * (float)t.hh[3];
    }

    const int rb = rowptr[wid], re = rowptr[wid + 1];
    int p = rb;
    for (; p + 8 <= re; p += 8) {
        // weight phase: lane computes w for edge i8, slot wsl
        int sval = csr_src[p + i8];
        float ee = as[(u32)sval * NS + wsl] + adv_w;
        ee = fmaxf(ee, 0.2f * ee);
        float wv = __expf(ee);
        // broadcast src ids and issue all 8 gathers
        int si[8];
        uint2 raw[8];
#pragma unroll
        for (int i = 0; i < 8; i++) si[i] = __shfl(sval, i, 64);
#pragma unroll
        for (int i = 0; i < 8; i++)
            raw[i] = *(const uint2*)(h + ((u32)si[i] << 8) + c);
        // accumulate
#pragma unroll
        for (int i = 0; i < 8; i++) {
            float wi = __shfl(wv, slot * 8 + i, 64);
            union { uint2 u; f16 hh[4]; } t;
            t.u = raw[i];
            denom += wi;
            acc0 += wi * (float)t.hh[0];
            acc1 += wi * (float)t.hh[1];
            acc2 += wi * (float)t.hh[2];
            acc3 += wi * (float)t.hh[3];
        }
    }
    for (; p < re; ++p) {  // tail (<8 edges)
        int s = csr_src[p];
        float ev = as[(u32)s * NS + slot] + adv_own;
        ev = fmaxf(ev, 0.2f * ev);
        float ww = __expf(ev);
        denom += ww;
        union { uint2 u; f16 hh[4]; } t;
        t.u = *(const uint2*)(h + ((u32)s << 8) + c);
        acc0 += ww * (float)t.hh[0];
        acc1 += ww * (float)t.hh[1];
        acc2 += ww * (float)t.hh[2];
        acc3 += ww * (float)t.hh[3];
    }
    float inv = 1.0f / (denom + 1e-16f);

    int ci = c & 127;
    const float* bp = (c < 128) ? b_lo : b_hi;
    float4 bv = *(const float4*)(bp + ci);
    float v0 = acc0 * inv + bv.x;
    float v1 = acc1 * inv + bv.y;
    float v2 = acc2 * inv + bv.z;
    float v3 = acc3 * inv + bv.w;

    if (MODE == 0) {  // ELU -> x1 fp16 [n,256]
        v0 = v0 > 0.f ? v0 : expm1f(v0);
        v1 = v1 > 0.f ? v1 : expm1f(v1);
        v2 = v2 > 0.f ? v2 : expm1f(v2);
        v3 = v3 > 0.f ? v3 : expm1f(v3);
        store4(outp, (size_t)wid * 256 + c, make_float4(v0, v1, v2, v3));
    } else {  // mu (c<128) then logstd, each [n,128] fp32, concatenated
        size_t base = (c < 128) ? ((size_t)wid * 128 + c)
                                : ((size_t)n * 128 + (size_t)wid * 128 + (c - 128));
        store4(outp, base, make_float4(v0, v1, v2, v3));
    }
}

// ---------------------------------------------------------------------------
extern "C" void kernel_launch(void* const* d_in, const int* in_sizes, int n_in,
                              void* d_out, int out_size, void* d_ws, size_t ws_size,
                              hipStream_t stream) {
    const float* x = (const float*)d_in[0];
    const u32* ebuf = (const u32*)d_in[1];
    const float* W1 = (const float*)d_in[2];
    const float* a_src1 = (const float*)d_in[3];
    const float* a_dst1 = (const float*)d_in[4];
    const float* b1 = (const float*)d_in[5];
    const float* W_mu = (const float*)d_in[6];
    const float* a_src_mu = (const float*)d_in[7];
    const float* a_dst_mu = (const float*)d_in[8];
    const float* b_mu = (const float*)d_in[9];
    const float* W_ls = (const float*)d_in[10];
    const float* a_src_ls = (const float*)d_in[11];
    const float* a_dst_ls = (const float*)d_in[12];
    const float* b_ls = (const float*)d_in[13];

    const int n = in_sizes[0] / 128;  // 50000
    const int E = in_sizes[1] / 2;    // 800000

    char* base = (char*)d_ws;
    size_t off = 0;
    auto alloc = [&](size_t b) -> char* {
        char* p = base + off;
        off = (off + b + 255) & ~(size_t)255;
        return p;
    };
    int* rowptr = (int*)alloc((size_t)(n + 1) * 4);
    int* cursor = (int*)alloc((size_t)n * 4);
    int* csr = (int*)alloc((size_t)E * 4);
    int* bsum = (int*)alloc(256 * 4);
    int* eflag = (int*)alloc(256);
    int* se = (int*)alloc((size_t)E * 4);
    int* de = (int*)alloc((size_t)E * 4);
    float* as = (float*)alloc((size_t)n * 4 * 4);
    float* ad = (float*)alloc((size_t)n * 4 * 4);
    u16* W1t = (u16*)alloc(256 * 128 * 2);        // W1^T fp16 [256][128]
    u16* Wt2 = (u16*)alloc(256 * 256 * 2);        // [W_mu|W_ls]^T fp16 [256][256]
    u16* x1h = (u16*)alloc((size_t)n * 256 * 2);  // x1 fp16 [n,256]
    u16* xh = x1h;  // alias: xh fp16 [n,128] dead before x1h written
    u16* h = (u16*)alloc((size_t)n * 256 * 2);    // h fp16 (both layers)

    const int nb = (n + 255) / 256;
    const int eg = (E + 255) / 256;
    const int ng4 = (n + 3) / 4;
    const int gg = (n + 63) / 64;
    const int nx4 = n * 128 / 4;
    const int B0 = (nx4 + 255) / 256;

    // edge normalize + CSR build (reused by all three convs)
    hipMemsetAsync(cursor, 0, (size_t)n * 4, stream);
    k_detect<<<1, 256, 0, stream>>>(ebuf, eflag);
    k_extract<<<eg, 256, 0, stream>>>(ebuf, E, eflag, se, de, cursor);
    k_scan_a<<<nb, 256, 0, stream>>>(cursor, n, bsum);
    k_scan_b<<<1, 256, 0, stream>>>(bsum, nb);
    k_scan_c<<<nb, 256, 0, stream>>>(cursor, n, bsum, rowptr, cursor, E);
    k_fill<<<eg, 256, 0, stream>>>(se, de, E, cursor, csr);

    // fp16 conversions + weight transposes (merged)
    k_prep<<<B0 + 128 + 256, 256, 0, stream>>>(x, xh, B0, nx4, W1, W1t, W_mu, W_ls,
                                               Wt2);

    // Layer 1: h = x@W1 (MFMA, fused alphas); aggregate -> ELU -> x1 (fp16)
    k_gemm_mfma<128, 5><<<gg, 128, 0, stream>>>(xh, W1t, h, as, ad, a_src1,
                                                a_src1 + 128, a_dst1, a_dst1 + 128,
                                                n);
    k_agg<5, 0, u16><<<ng4, 256, 0, stream>>>(h, rowptr, csr, as, ad, b1, b1 + 128,
                                              x1h, n);

    // Layers mu & ls: h = x1@[W_mu|W_ls] (MFMA, fused alphas); aggregate
    k_gemm_mfma<256, 4><<<gg, 128, 0, stream>>>(x1h, Wt2, h, as, ad, a_src_mu,
                                                a_src_ls, a_dst_mu, a_dst_ls, n);
    k_agg<4, 1, float><<<ng4, 256, 0, stream>>>(h, rowptr, csr, as, ad, b_mu, b_ls,
                                                (float*)d_out, n);
}